// Round 11
// baseline (358.422 us; speedup 1.0000x reference)
//
#include <hip/hip_runtime.h>
#include <hip/hip_bf16.h>

typedef __hip_bfloat16 bf16;
typedef __attribute__((ext_vector_type(8))) short bf16x8;  // 8 bf16 = 16B
typedef __attribute__((ext_vector_type(4))) float f32x4;

#define AS1 __attribute__((address_space(1)))
#define AS3 __attribute__((address_space(3)))

__device__ __forceinline__ void async16(const void* g, void* l) {
  __builtin_amdgcn_global_load_lds((const AS1 void*)g, (AS3 void*)l, 16, 0, 0);
}

__device__ __forceinline__ float fsigmoid(float x) { return 1.0f / (1.0f + __expf(-x)); }
__device__ __forceinline__ float ftanh(float x)    { return 1.0f - 2.0f / (__expf(2.0f * x) + 1.0f); }

__device__ __forceinline__ bf16x8 pack8(float4 lo, float4 hi) {
  union { bf16x8 v; unsigned int u[4]; } r;
  r.u[0] = (__float_as_uint(lo.y) & 0xFFFF0000u) | (__float_as_uint(lo.x) >> 16);
  r.u[1] = (__float_as_uint(lo.w) & 0xFFFF0000u) | (__float_as_uint(lo.z) >> 16);
  r.u[2] = (__float_as_uint(hi.y) & 0xFFFF0000u) | (__float_as_uint(hi.x) >> 16);
  r.u[3] = (__float_as_uint(hi.w) & 0xFFFF0000u) | (__float_as_uint(hi.z) >> 16);
  return r.v;
}

// ---- prep: fp32 -> bf16 into ws.
// Layout: A[8192][2048] (x | h along K), then W'[4096][2048] where
// n' = (h>>6)*256 + gate*64 + (h&63); cols 0..1023 = W_i, 1024.. = W_h.
__global__ __launch_bounds__(256) void prep_bf16(
    const float* __restrict__ x, const float* __restrict__ h,
    const float* __restrict__ wfi, const float* __restrict__ wii,
    const float* __restrict__ wgi, const float* __restrict__ woi,
    const float* __restrict__ wfh, const float* __restrict__ wih,
    const float* __restrict__ wgh, const float* __restrict__ woh,
    bf16* __restrict__ dst)
{
  const int NC = 3 * 1024 * 1024;
  for (int ci = blockIdx.x * 256 + threadIdx.x; ci < NC; ci += gridDim.x * 256) {
    const float* src; size_t soff, doff;
    if (ci < (1 << 20)) {                       // x
      int m = ci >> 7, k = (ci & 127) << 3;
      src = x; soff = (size_t)m * 1024 + k; doff = (size_t)m * 2048 + k;
    } else if (ci < (2 << 20)) {                // h
      int c2 = ci - (1 << 20);
      int m = c2 >> 7, k = (c2 & 127) << 3;
      src = h; soff = (size_t)m * 1024 + k; doff = (size_t)m * 2048 + 1024 + k;
    } else {                                    // weights
      int we  = ci - (2 << 20);
      int mat = we >> 17;
      int wl  = we & ((1 << 17) - 1);
      int hh  = wl >> 7, k = (wl & 127) << 3;
      int g   = mat & 3;
      src = (mat == 0) ? wfi : (mat == 1) ? wii : (mat == 2) ? wgi : (mat == 3) ? woi
          : (mat == 4) ? wfh : (mat == 5) ? wih : (mat == 6) ? wgh : woh;
      soff = (size_t)hh * 1024 + k;
      doff = (size_t)8192 * 2048
           + (size_t)(((hh >> 6) << 8) + (g << 6) + (hh & 63)) * 2048
           + ((mat >> 2) << 10) + k;
    }
    float4 lo = *(const float4*)(src + soff);
    float4 hi = *(const float4*)(src + soff + 4);
    *(bf16x8*)(dst + doff) = pack8(lo, hi);
  }
}

// ---- main: 256x256 tile, BK=64, 8 waves.
// Round-6: MERGED phases — 2 phases per K-tile (one per kh-half), each with
// 32 MFMA/wave + 12 ds_read_b128 + 4 async16 + 2 barriers. Halves the per-tile
// barrier count (8->4): rounds 3/5 showed ~1100 cyc/phase FIXED overhead
// (frag-prefetch null), so amortizing it over 2x MFMA is the lever.
// Ledger (per wave, 4 loads per kh-set): stage map E_kh(t) stages (t+1,kh);
// steady state 8 outstanding; each phase ends vmcnt(4) retiring the kh-set
// staged ONE phase earlier (lead ~2000cyc >> HBM ~900cyc). Double-buffered
// LDS by tile parity => stages never overwrite the buffer being read (no WAR).
#define VMCNT(N) do { asm volatile("s_waitcnt vmcnt(" #N ")" ::: "memory"); \
                      __builtin_amdgcn_sched_barrier(0); } while (0)

#define BAR __builtin_amdgcn_s_barrier()

// One merged phase: reads + stage BEFORE mid-barrier, MFMA cluster after,
// then optional vmcnt retire + end-barrier (cross-wave visibility for the
// kh-set the NEXT phase reads).
#define PHASE(t_, kh_, STAGE_STMT, VMW)                                       \
  {                                                                           \
    const char* Ab_ = smem + (((t_) & 1) << 16) + ((kh_) << 14);              \
    const char* Bb_ = Ab_ + 32768;                                            \
    bf16x8 af[8], bf[4];                                                      \
    _Pragma("unroll") for (int i_ = 0; i_ < 8; ++i_)                          \
      af[i_] = *(const bf16x8*)(Ab_ + aoff + (i_ << 10));                     \
    _Pragma("unroll") for (int n_ = 0; n_ < 4; ++n_)                          \
      bf[n_] = *(const bf16x8*)(Bb_ + boff + (n_ << 10));                     \
    STAGE_STMT;                                                               \
    BAR;                                                                      \
    __builtin_amdgcn_s_setprio(1);                                            \
    _Pragma("unroll") for (int i_ = 0; i_ < 8; ++i_)                          \
      _Pragma("unroll") for (int n_ = 0; n_ < 4; ++n_)                        \
        acc[i_][n_] = __builtin_amdgcn_mfma_f32_16x16x32_bf16(                \
            af[i_], bf[n_], acc[i_][n_], 0, 0, 0);                            \
    __builtin_amdgcn_s_setprio(0);                                            \
    VMW;                                                                      \
    BAR;                                                                      \
  }

__global__ __launch_bounds__(512, 2) void lstm_mfma(
    const bf16* __restrict__ ws,
    const float* __restrict__ c,
    const float* __restrict__ bfi, const float* __restrict__ bfh,
    const float* __restrict__ bii, const float* __restrict__ bih,
    const float* __restrict__ bgi, const float* __restrict__ bgh,
    const float* __restrict__ boi, const float* __restrict__ boh,
    float* __restrict__ out)
{
  __shared__ __align__(16) char smem[135168];

  const int tid  = threadIdx.x;
  const int lane = tid & 63;
  const int w    = tid >> 6;
  const int wr   = w >> 2;        // M half
  const int wc   = w & 3;         // N quarter == gate
  const int l15  = lane & 15;
  const int quad = lane >> 4;

  // T1: 2D-chunked XCD map (8 XCD x 64 blocks; 8x8 block region per XCD).
  const int orig = blockIdx.x;
  const int xcd  = orig & 7;
  const int li   = orig >> 3;
  const int by   = ((xcd >> 1) << 3) + (li & 7);   // 0..31
  const int bx   = ((xcd & 1) << 3) + (li >> 3);   // 0..15
  const int bg0  = by << 8;

  const bf16* Ag = ws + (size_t)bg0 * 2048;
  const bf16* Bg = ws + (size_t)8192 * 2048 + (size_t)(bx << 8) * 2048;

  // staging: lane -> (row r2 = lane>>2, dest slot sl = lane&3); LDS slot s at
  // row r holds global chunk s ^ ((r>>1)&3); source pre-swizzled accordingly.
  const int r2 = lane >> 2;
  const int sl = lane & 3;
  const int schunk = ((sl ^ ((r2 >> 1) & 3)) << 3);   // elems

  // frag reads: slot = quad ^ ((row>>1)&3)  (row stride 64B = 16 banks, period 2
  // in bank space -> covers all 8 bank-quads 2x per quarter-wave = free 2-way).
  const int slotA = ((quad ^ ((l15 >> 1) & 3)) << 4); // bytes
  const int aoff  = ((wr << 7) + l15) * 64 + slotA;
  const int boff  = ((wc << 6) + l15) * 64 + slotA;

  f32x4 acc[8][4];
#pragma unroll
  for (int i = 0; i < 8; ++i)
#pragma unroll
    for (int j = 0; j < 4; ++j) acc[i][j] = (f32x4){0.f, 0.f, 0.f, 0.f};

  auto stageA = [&](int t_, int kh_) {
    const bf16* s = Ag + (size_t)(t_ << 6) + (kh_ << 5) + schunk;
    char* d = smem + ((t_ & 1) << 16) + (kh_ << 14) + (w << 10);
#pragma unroll
    for (int r = 0; r < 2; ++r)
      async16(s + ((size_t)((((r << 3) + w) << 4) + r2)) * 2048, d + (r << 13));
  };
  auto stageB = [&](int t_, int kh_) {
    const bf16* s = Bg + (size_t)(t_ << 6) + (kh_ << 5) + schunk;
    char* d = smem + ((t_ & 1) << 16) + 32768 + (kh_ << 14) + (w << 10);
#pragma unroll
    for (int r = 0; r < 2; ++r)
      async16(s + ((size_t)((((r << 3) + w) << 4) + r2)) * 2048, d + (r << 13));
  };

  // Prologue: stage tile-0 both kh-sets (8 loads); vmcnt(4) retires (0,0);
  // barrier -> cross-wave visible.
  stageA(0, 0); stageB(0, 0); stageA(0, 1); stageB(0, 1);
  VMCNT(4);
  BAR;

  // Steady state: E0(t) stages (t+1,0), retires (t,1)  [staged E1(t-1), or
  // prologue for t=0 -- ledger: end E0(t) outstanding (t,1)+(t+1,0)=8 ->
  // vmcnt(4) retires (t,1), read by E1(t)].  E1(t) stages (t+1,1), retires
  // (t+1,0) [outstanding (t+1,0)+(t+1,1)=8 -> vmcnt(4)], read by E0(t+1).
  for (int t = 0; t < 31; ++t) {
    PHASE(t, 0, { stageA(t + 1, 0); stageB(t + 1, 0); }, VMCNT(4))
    PHASE(t, 1, { stageA(t + 1, 1); stageB(t + 1, 1); }, VMCNT(4))
  }
  {  // t = 31: nothing to stage; retire (31,1) before E1 reads it
    PHASE(31, 0, , VMCNT(0))
    PHASE(31, 1, , )
  }

  // ---- fused LSTM epilogue: two row-half passes through Act[4][128][66] f32.
  float* Act = (float*)smem;
  const float* bI = (wc == 0) ? bfi : (wc == 1) ? bii : (wc == 2) ? bgi : boi;
  const float* bH = (wc == 0) ? bfh : (wc == 1) ? bih : (wc == 2) ? bgh : boh;
  const int hcol0 = bx << 6;
  float biasv[4];
#pragma unroll
  for (int n = 0; n < 4; ++n)
    biasv[n] = bI[hcol0 + n * 16 + l15] + bH[hcol0 + n * 16 + l15];

  const size_t outCT = (size_t)8192 * 1024;
  const bool istanh = (wc == 2);

#pragma unroll
  for (int p = 0; p < 2; ++p) {
    __syncthreads();
    if (wr == p) {
      float* Aw = Act + wc * 8448;   // [128][66]
#pragma unroll
      for (int m = 0; m < 8; ++m)
#pragma unroll
        for (int n = 0; n < 4; ++n)
#pragma unroll
          for (int r = 0; r < 4; ++r) {
            const float v = acc[m][n][r] + biasv[n];
            Aw[(m * 16 + quad * 4 + r) * 66 + n * 16 + l15] = istanh ? ftanh(v) : fsigmoid(v);
          }
    }
    __syncthreads();
#pragma unroll
    for (int it = 0; it < 16; ++it) {
      const int idx = it * 512 + tid;
      const int row = idx >> 6, col = idx & 63;
      const float fv = Act[row * 66 + col];
      const float iv = Act[8448 + row * 66 + col];
      const float gv = Act[16896 + row * 66 + col];
      const float ov = Act[25344 + row * 66 + col];
      const size_t gi = (size_t)(bg0 + p * 128 + row) * 1024 + hcol0 + col;
      const float ctv = fv * c[gi] + iv * gv;
      const float htv = ov * ftanh(ctv);
      out[gi]         = htv;
      out[outCT + gi] = ctv;
    }
  }
}

// ---- fallback (register staging, original layout) if ws too small ----
__global__ __launch_bounds__(256) void lstm_fused(
    const float* __restrict__ x, const float* __restrict__ h, const float* __restrict__ c,
    const float* __restrict__ wfi, const float* __restrict__ bfi, const float* __restrict__ wfh, const float* __restrict__ bfh,
    const float* __restrict__ wii, const float* __restrict__ bii, const float* __restrict__ wih, const float* __restrict__ bih,
    const float* __restrict__ wgi, const float* __restrict__ bgi, const float* __restrict__ wgh, const float* __restrict__ bgh,
    const float* __restrict__ woi, const float* __restrict__ boi, const float* __restrict__ woh, const float* __restrict__ boh,
    float* __restrict__ out)
{
  __shared__ __align__(16) char smem[33792];
  short* As = (short*)smem;
  short* Bs = As + 8192;
  float* Epi = (float*)smem;

  const int tid  = threadIdx.x;
  const int lane = tid & 63;
  const int w    = tid >> 6;
  const int l15  = lane & 15;
  const int quad = lane >> 4;
  const int rq   = w >> 1;
  const int cq   = w & 1;
  const int rowoff = lane >> 3;
  const int ch   = lane & 7;
  const int dstch = ch ^ rowoff;

  const int bg0 = blockIdx.y << 7;
  const int hb  = blockIdx.x << 5;

  const float* WgI = (w == 0) ? wfi : (w == 1) ? wii : (w == 2) ? wgi : woi;
  const float* WgH = (w == 0) ? wfh : (w == 1) ? wih : (w == 2) ? wgh : woh;

  size_t aoff[4], boff2[4];
#pragma unroll
  for (int q = 0; q < 4; ++q) {
    const int u = (w << 2) + q;
    aoff[q]  = (size_t)((u << 3) + rowoff) * 1024 + (ch << 3);
    boff2[q] = (size_t)((q << 3) + rowoff) * 1024 + (ch << 3);
  }

  f32x4 acc[4][4];
#pragma unroll
  for (int i = 0; i < 4; ++i)
#pragma unroll
    for (int j = 0; j < 4; ++j) acc[i][j] = (f32x4){0.f, 0.f, 0.f, 0.f};

  const int arow = (rq * 64 + l15) * 64;
  const int brow = (cq * 64 + l15) * 64;
  const int sw   = l15 & 7;
  const int c0   = ((0 + quad) ^ sw) << 3;
  const int c1   = ((4 + quad) ^ sw) << 3;

  float4 A0[4], A1[4], B0[4], B1[4];
  auto issue = [&](int KT) {
    const float* Ab = ((KT < 16) ? x : h)     + (size_t)bg0 * 1024 + ((KT & 15) << 6);
    const float* Bb = ((KT < 16) ? WgI : WgH) + (size_t)hb  * 1024 + ((KT & 15) << 6);
#pragma unroll
    for (int q = 0; q < 4; ++q) {
      const float* pa = Ab + aoff[q];
      const float* pb = Bb + boff2[q];
      A0[q] = *(const float4*)pa; A1[q] = *(const float4*)(pa + 4);
      B0[q] = *(const float4*)pb; B1[q] = *(const float4*)(pb + 4);
    }
  };

  issue(0);
  for (int kt = 0; kt < 32; ++kt) {
    __syncthreads();
#pragma unroll
    for (int q = 0; q < 4; ++q) {
      const int u = (w << 2) + q;
      *(bf16x8*)(As + (u * 8 + rowoff) * 64 + (dstch << 3)) = pack8(A0[q], A1[q]);
      *(bf16x8*)(Bs + (u * 8 + rowoff) * 64 + (dstch << 3)) = pack8(B0[q], B1[q]);
    }
    __syncthreads();
    if (kt < 31) issue(kt + 1);

#pragma unroll
    for (int s = 0; s < 2; ++s) {
      const int cs = s ? c1 : c0;
      bf16x8 a[4], b[4];
#pragma unroll
      for (int i = 0; i < 4; ++i) a[i] = *(const bf16x8*)(As + arow + i * 1024 + cs);
#pragma unroll
      for (int j = 0; j < 4; ++j) b[j] = *(const bf16x8*)(Bs + brow + j * 1024 + cs);
#pragma unroll
      for (int i = 0; i < 4; ++i)
#pragma unroll
        for (int j = 0; j < 4; ++j)
          acc[i][j] = __builtin_amdgcn_mfma_f32_16x16x32_bf16(a[i], b[j], acc[i][j], 0, 0, 0);
    }
  }

  const float* bAi = cq ? bgi : bfi;
  const float* bAh = cq ? bgh : bfh;
  const float* bBi = cq ? boi : bii;
  const float* bBh = cq ? boh : bih;
  float biasv[4];
  biasv[0] = bAi[hb + l15]      + bAh[hb + l15];
  biasv[1] = bAi[hb + 16 + l15] + bAh[hb + 16 + l15];
  biasv[2] = bBi[hb + l15]      + bBh[hb + l15];
  biasv[3] = bBi[hb + 16 + l15] + bBh[hb + 16 + l15];

  const size_t outCT = (size_t)8192 * 1024;

#pragma unroll
  for (int p = 0; p < 2; ++p) {
    __syncthreads();
    if (rq == p) {
#pragma unroll
      for (int j = 0; j < 4; ++j) {
        const int  n  = cq * 64 + j * 16 + l15;
        const bool ut = (cq == 1) && (j < 2);
        const float bj = biasv[j];
#pragma unroll
        for (int i = 0; i < 4; ++i)
#pragma unroll
          for (int r = 0; r < 4; ++r) {
            const float v = acc[i][j][r] + bj;
            Epi[(i * 16 + quad * 4 + r) * 132 + n] = ut ? ftanh(v) : fsigmoid(v);
          }
      }
    }
    __syncthreads();
#pragma unroll
    for (int it = 0; it < 8; ++it) {
      const int pair = it * 256 + tid;
      const int row  = pair >> 5;
      const int hl   = pair & 31;
      const float fv = Epi[row * 132 + hl];
      const float iv = Epi[row * 132 + 32 + hl];
      const float gv = Epi[row * 132 + 64 + hl];
      const float ov = Epi[row * 132 + 96 + hl];
      const size_t idx = (size_t)(bg0 + p * 64 + row) * 1024 + hb + hl;
      const float ctv = fv * c[idx] + iv * gv;
      const float htv = ov * ftanh(ctv);
      out[idx]         = htv;
      out[outCT + idx] = ctv;
    }
  }
}

extern "C" void kernel_launch(void* const* d_in, const int* in_sizes, int n_in,
                              void* d_out, int out_size, void* d_ws, size_t ws_size,
                              hipStream_t stream) {
  const float* p[19];
  for (int i = 0; i < 19; ++i) p[i] = (const float*)d_in[i];
  const size_t need = (size_t)24 * 1024 * 1024 * sizeof(bf16);   // 48 MB
  if (ws_size >= need) {
    prep_bf16<<<dim3(2048), dim3(256), 0, stream>>>(
        p[0], p[1],
        p[3], p[7], p[11], p[15],     // wfi wii wgi woi
        p[5], p[9], p[13], p[17],     // wfh wih wgh woh
        (bf16*)d_ws);
    lstm_mfma<<<dim3(512), dim3(512), 0, stream>>>(
        (const bf16*)d_ws, p[2],
        p[4], p[6], p[8], p[10], p[12], p[14], p[16], p[18],
        (float*)d_out);
  } else {
    lstm_fused<<<dim3(32, 64), dim3(256), 0, stream>>>(
        p[0], p[1], p[2],
        p[3], p[4], p[5], p[6],
        p[7], p[8], p[9], p[10],
        p[11], p[12], p[13], p[14],
        p[15], p[16], p[17], p[18],
        (float*)d_out);
  }
}

// Round 14
// 352.313 us; speedup vs baseline: 1.0173x; 1.0173x over previous
//
#include <hip/hip_runtime.h>
#include <hip/hip_bf16.h>

typedef __hip_bfloat16 bf16;
typedef __attribute__((ext_vector_type(8))) short bf16x8;  // 8 bf16 = 16B
typedef __attribute__((ext_vector_type(4))) float f32x4;

#define AS1 __attribute__((address_space(1)))
#define AS3 __attribute__((address_space(3)))

__device__ __forceinline__ void async16(const void* g, void* l) {
  __builtin_amdgcn_global_load_lds((const AS1 void*)g, (AS3 void*)l, 16, 0, 0);
}

__device__ __forceinline__ float fsigmoid(float x) { return 1.0f / (1.0f + __expf(-x)); }
__device__ __forceinline__ float ftanh(float x)    { return 1.0f - 2.0f / (__expf(2.0f * x) + 1.0f); }

__device__ __forceinline__ bf16x8 pack8(float4 lo, float4 hi) {
  union { bf16x8 v; unsigned int u[4]; } r;
  r.u[0] = (__float_as_uint(lo.y) & 0xFFFF0000u) | (__float_as_uint(lo.x) >> 16);
  r.u[1] = (__float_as_uint(lo.w) & 0xFFFF0000u) | (__float_as_uint(lo.z) >> 16);
  r.u[2] = (__float_as_uint(hi.y) & 0xFFFF0000u) | (__float_as_uint(hi.x) >> 16);
  r.u[3] = (__float_as_uint(hi.w) & 0xFFFF0000u) | (__float_as_uint(hi.z) >> 16);
  return r.v;
}

// ---- prep: fp32 -> bf16 into ws.
// Layout: A[8192][2048] (x | h along K), then W'[4096][2048] where
// n' = (h>>6)*256 + gate*64 + (h&63); cols 0..1023 = W_i, 1024.. = W_h.
__global__ __launch_bounds__(256) void prep_bf16(
    const float* __restrict__ x, const float* __restrict__ h,
    const float* __restrict__ wfi, const float* __restrict__ wii,
    const float* __restrict__ wgi, const float* __restrict__ woi,
    const float* __restrict__ wfh, const float* __restrict__ wih,
    const float* __restrict__ wgh, const float* __restrict__ woh,
    bf16* __restrict__ dst)
{
  const int NC = 3 * 1024 * 1024;
  for (int ci = blockIdx.x * 256 + threadIdx.x; ci < NC; ci += gridDim.x * 256) {
    const float* src; size_t soff, doff;
    if (ci < (1 << 20)) {                       // x
      int m = ci >> 7, k = (ci & 127) << 3;
      src = x; soff = (size_t)m * 1024 + k; doff = (size_t)m * 2048 + k;
    } else if (ci < (2 << 20)) {                // h
      int c2 = ci - (1 << 20);
      int m = c2 >> 7, k = (c2 & 127) << 3;
      src = h; soff = (size_t)m * 1024 + k; doff = (size_t)m * 2048 + 1024 + k;
    } else {                                    // weights
      int we  = ci - (2 << 20);
      int mat = we >> 17;
      int wl  = we & ((1 << 17) - 1);
      int hh  = wl >> 7, k = (wl & 127) << 3;
      int g   = mat & 3;
      src = (mat == 0) ? wfi : (mat == 1) ? wii : (mat == 2) ? wgi : (mat == 3) ? woi
          : (mat == 4) ? wfh : (mat == 5) ? wih : (mat == 6) ? wgh : woh;
      soff = (size_t)hh * 1024 + k;
      doff = (size_t)8192 * 2048
           + (size_t)(((hh >> 6) << 8) + (g << 6) + (hh & 63)) * 2048
           + ((mat >> 2) << 10) + k;
    }
    float4 lo = *(const float4*)(src + soff);
    float4 hi = *(const float4*)(src + soff + 4);
    *(bf16x8*)(dst + doff) = pack8(lo, hi);
  }
}

// ---- main: 256x256 tile, BK=64, 8 waves, 4-phase/K-tile (R3 structure).
// Round-12 deltas vs R3 (183.6us, MfmaUtil 32%):
//  (a) explicit lgkmcnt(0) AFTER the pre-MFMA barrier (m201 letter): pins the
//      ds_reads before the barrier (memory clobber) so read-drain overlaps
//      barrier-wait, and the MFMA cluster runs with no mid-cluster lgkm stalls.
//  (b) VMCNT without sched_barrier(0) (m141: order-pinning hurts; "memory"
//      clobber alone fences subsequent LDS reads).
//  (c) staging/read addressing hoisted to loop-invariant bases (VALUBusy 25%
//      suggests per-phase address recomputation).
#define VMCNT(N) asm volatile("s_waitcnt vmcnt(" #N ")" ::: "memory")

#define BAR __builtin_amdgcn_s_barrier()

#define PH(pb_, kh_, mh_, STAGE_STMT, VMW)                                    \
  {                                                                           \
    const char* Ab_ = (pb_) + ((kh_) << 14);                                  \
    const char* Bb_ = Ab_ + 32768;                                            \
    if ((mh_) == 0) {                                                         \
      _Pragma("unroll") for (int n_ = 0; n_ < 4; ++n_)                        \
        bfr[n_] = *(const bf16x8*)(Bb_ + boff + (n_ << 10));                  \
    }                                                                         \
    bf16x8 afr[4];                                                            \
    _Pragma("unroll") for (int i_ = 0; i_ < 4; ++i_)                          \
      afr[i_] = *(const bf16x8*)(Ab_ + aoff + ((((mh_) << 2) + i_) << 10));   \
    STAGE_STMT;                                                               \
    __builtin_amdgcn_s_barrier();                                             \
    asm volatile("s_waitcnt lgkmcnt(0)" ::: "memory");                        \
    __builtin_amdgcn_s_setprio(1);                                            \
    _Pragma("unroll") for (int i_ = 0; i_ < 4; ++i_)                          \
      _Pragma("unroll") for (int n_ = 0; n_ < 4; ++n_)                        \
        acc[((mh_) << 2) + i_][n_] = __builtin_amdgcn_mfma_f32_16x16x32_bf16( \
            afr[i_], bfr[n_], acc[((mh_) << 2) + i_][n_], 0, 0, 0);           \
    __builtin_amdgcn_s_setprio(0);                                            \
    VMW;                                                                      \
    __builtin_amdgcn_s_barrier();                                             \
  }

__global__ __launch_bounds__(512, 2) void lstm_mfma(
    const bf16* __restrict__ ws,
    const float* __restrict__ c,
    const float* __restrict__ bfi, const float* __restrict__ bfh,
    const float* __restrict__ bii, const float* __restrict__ bih,
    const float* __restrict__ bgi, const float* __restrict__ bgh,
    const float* __restrict__ boi, const float* __restrict__ boh,
    float* __restrict__ out)
{
  __shared__ __align__(16) char smem[135168];

  const int tid  = threadIdx.x;
  const int lane = tid & 63;
  const int w    = tid >> 6;
  const int wr   = w >> 2;        // M half
  const int wc   = w & 3;         // N quarter == gate
  const int l15  = lane & 15;
  const int quad = lane >> 4;

  // T1: 2D-chunked XCD map (8 XCD x 64 blocks; 8x8 block region per XCD).
  const int orig = blockIdx.x;
  const int xcd  = orig & 7;
  const int li   = orig >> 3;
  const int by   = ((xcd >> 1) << 3) + (li & 7);   // 0..31
  const int bx   = ((xcd & 1) << 3) + (li >> 3);   // 0..15
  const int bg0  = by << 8;

  const bf16* Ag = ws + (size_t)bg0 * 2048;
  const bf16* Bg = ws + (size_t)8192 * 2048 + (size_t)(bx << 8) * 2048;

  // staging: lane -> (row r2 = lane>>2, dest slot sl = lane&3); LDS slot s at
  // row r holds global chunk s ^ ((r>>1)&3); source pre-swizzled accordingly.
  const int r2 = lane >> 2;
  const int sl = lane & 3;
  const int schunk = ((sl ^ ((r2 >> 1) & 3)) << 3);   // elems

  // frag reads: slot = quad ^ ((row>>1)&3)  (row stride 64B = 16 banks, period 2
  // in bank space -> covers all 8 bank-quads 2x per quarter-wave = free 2-way).
  const int slotA = ((quad ^ ((l15 >> 1) & 3)) << 4); // bytes
  const int aoff  = ((wr << 7) + l15) * 64 + slotA;
  const int boff  = ((wc << 6) + l15) * 64 + slotA;

  f32x4 acc[8][4];
#pragma unroll
  for (int i = 0; i < 8; ++i)
#pragma unroll
    for (int j = 0; j < 4; ++j) acc[i][j] = (f32x4){0.f, 0.f, 0.f, 0.f};

  // (c) hoisted staging bases: global row offsets (lane-dependent, invariant)
  const size_t sr0 = (size_t)((w << 4) + r2) * 2048;         // r=0 row
  const size_t sr1 = (size_t)(((8 + w) << 4) + r2) * 2048;   // r=1 row
  const bf16* AgS = Ag + schunk;
  const bf16* BgS = Bg + schunk;
  char* aD = smem + (w << 10);
  char* bD = smem + 32768 + (w << 10);

  auto stageA = [&](int t_, int kh_) {
    const bf16* s = AgS + (t_ << 6) + (kh_ << 5);
    char* d = aD + ((t_ & 1) << 16) + (kh_ << 14);
    async16(s + sr0, d);
    async16(s + sr1, d + 8192);
  };
  auto stageB = [&](int t_, int kh_) {
    const bf16* s = BgS + (t_ << 6) + (kh_ << 5);
    char* d = bD + ((t_ & 1) << 16) + (kh_ << 14);
    async16(s + sr0, d);
    async16(s + sr1, d + 8192);
  };

  // Prologue: 6 stage calls = 12 loads; vmcnt(8) retires A(0,0),B(0,0);
  // barrier -> cross-wave visible. (R3 ledger, HW-verified.)
  stageA(0, 0); stageB(0, 0); stageA(0, 1); stageB(0, 1); stageA(1, 0); stageB(1, 0);
  VMCNT(8);
  BAR;

  // Steady: q0->A(t+1,1), q1->B(t+1,1)+VMCNT(8) [drains A/B(t,1) for q2/q3],
  // q2->A(t+2,0), q3->B(t+2,0)+VMCNT(8) [drains A/B(t+1,0) for next q0/q1].
  for (int t = 0; t < 30; ++t) {
    const char* pb = smem + ((t & 1) << 16);
    bf16x8 bfr[4];
    PH(pb, 0, 0, { stageA(t + 1, 1); }, )
    PH(pb, 0, 1, { stageB(t + 1, 1); }, VMCNT(8))
    PH(pb, 1, 0, { stageA(t + 2, 0); }, )
    PH(pb, 1, 1, { stageB(t + 2, 0); }, VMCNT(8))
  }
  {  // t = 30: no t+2 stages; q3 wait shrinks to the 4 loads issued after B(31,0)
    const char* pb = smem;          // t=30 even -> buf0
    bf16x8 bfr[4];
    PH(pb, 0, 0, { stageA(31, 1); }, )
    PH(pb, 0, 1, { stageB(31, 1); }, VMCNT(8))
    PH(pb, 1, 0, , )
    PH(pb, 1, 1, , VMCNT(4))
  }
  {  // t = 31: drain tail
    const char* pb = smem + (1 << 16);
    bf16x8 bfr[4];
    PH(pb, 0, 0, , )
    PH(pb, 0, 1, , VMCNT(0))
    PH(pb, 1, 0, , )
    PH(pb, 1, 1, , )
  }

  // ---- fused LSTM epilogue: two row-half passes through Act[4][128][66] f32.
  float* Act = (float*)smem;
  const float* bI = (wc == 0) ? bfi : (wc == 1) ? bii : (wc == 2) ? bgi : boi;
  const float* bH = (wc == 0) ? bfh : (wc == 1) ? bih : (wc == 2) ? bgh : boh;
  const int hcol0 = bx << 6;
  float biasv[4];
#pragma unroll
  for (int n = 0; n < 4; ++n)
    biasv[n] = bI[hcol0 + n * 16 + l15] + bH[hcol0 + n * 16 + l15];

  const size_t outCT = (size_t)8192 * 1024;
  const bool istanh = (wc == 2);

#pragma unroll
  for (int p = 0; p < 2; ++p) {
    __syncthreads();
    if (wr == p) {
      float* Aw = Act + wc * 8448;   // [128][66]
#pragma unroll
      for (int m = 0; m < 8; ++m)
#pragma unroll
        for (int n = 0; n < 4; ++n)
#pragma unroll
          for (int r = 0; r < 4; ++r) {
            const float v = acc[m][n][r] + biasv[n];
            Aw[(m * 16 + quad * 4 + r) * 66 + n * 16 + l15] = istanh ? ftanh(v) : fsigmoid(v);
          }
    }
    __syncthreads();
#pragma unroll
    for (int it = 0; it < 16; ++it) {
      const int idx = it * 512 + tid;
      const int row = idx >> 6, col = idx & 63;
      const float fv = Act[row * 66 + col];
      const float iv = Act[8448 + row * 66 + col];
      const float gv = Act[16896 + row * 66 + col];
      const float ov = Act[25344 + row * 66 + col];
      const size_t gi = (size_t)(bg0 + p * 128 + row) * 1024 + hcol0 + col;
      const float ctv = fv * c[gi] + iv * gv;
      const float htv = ov * ftanh(ctv);
      out[gi]         = htv;
      out[outCT + gi] = ctv;
    }
  }
}

// ---- fallback (register staging, original layout) if ws too small ----
__global__ __launch_bounds__(256) void lstm_fused(
    const float* __restrict__ x, const float* __restrict__ h, const float* __restrict__ c,
    const float* __restrict__ wfi, const float* __restrict__ bfi, const float* __restrict__ wfh, const float* __restrict__ bfh,
    const float* __restrict__ wii, const float* __restrict__ bii, const float* __restrict__ wih, const float* __restrict__ bih,
    const float* __restrict__ wgi, const float* __restrict__ bgi, const float* __restrict__ wgh, const float* __restrict__ bgh,
    const float* __restrict__ woi, const float* __restrict__ boi, const float* __restrict__ woh, const float* __restrict__ boh,
    float* __restrict__ out)
{
  __shared__ __align__(16) char smem[33792];
  short* As = (short*)smem;
  short* Bs = As + 8192;
  float* Epi = (float*)smem;

  const int tid  = threadIdx.x;
  const int lane = tid & 63;
  const int w    = tid >> 6;
  const int l15  = lane & 15;
  const int quad = lane >> 4;
  const int rq   = w >> 1;
  const int cq   = w & 1;
  const int rowoff = lane >> 3;
  const int ch   = lane & 7;
  const int dstch = ch ^ rowoff;

  const int bg0 = blockIdx.y << 7;
  const int hb  = blockIdx.x << 5;

  const float* WgI = (w == 0) ? wfi : (w == 1) ? wii : (w == 2) ? wgi : woi;
  const float* WgH = (w == 0) ? wfh : (w == 1) ? wih : (w == 2) ? wgh : woh;

  size_t aoff[4], boff2[4];
#pragma unroll
  for (int q = 0; q < 4; ++q) {
    const int u = (w << 2) + q;
    aoff[q]  = (size_t)((u << 3) + rowoff) * 1024 + (ch << 3);
    boff2[q] = (size_t)((q << 3) + rowoff) * 1024 + (ch << 3);
  }

  f32x4 acc[4][4];
#pragma unroll
  for (int i = 0; i < 4; ++i)
#pragma unroll
    for (int j = 0; j < 4; ++j) acc[i][j] = (f32x4){0.f, 0.f, 0.f, 0.f};

  const int arow = (rq * 64 + l15) * 64;
  const int brow = (cq * 64 + l15) * 64;
  const int sw   = l15 & 7;
  const int c0   = ((0 + quad) ^ sw) << 3;
  const int c1   = ((4 + quad) ^ sw) << 3;

  float4 A0[4], A1[4], B0[4], B1[4];
  auto issue = [&](int KT) {
    const float* Ab = ((KT < 16) ? x : h)     + (size_t)bg0 * 1024 + ((KT & 15) << 6);
    const float* Bb = ((KT < 16) ? WgI : WgH) + (size_t)hb  * 1024 + ((KT & 15) << 6);
#pragma unroll
    for (int q = 0; q < 4; ++q) {
      const float* pa = Ab + aoff[q];
      const float* pb = Bb + boff2[q];
      A0[q] = *(const float4*)pa; A1[q] = *(const float4*)(pa + 4);
      B0[q] = *(const float4*)pb; B1[q] = *(const float4*)(pb + 4);
    }
  };

  issue(0);
  for (int kt = 0; kt < 32; ++kt) {
    __syncthreads();
#pragma unroll
    for (int q = 0; q < 4; ++q) {
      const int u = (w << 2) + q;
      *(bf16x8*)(As + (u * 8 + rowoff) * 64 + (dstch << 3)) = pack8(A0[q], A1[q]);
      *(bf16x8*)(Bs + (u * 8 + rowoff) * 64 + (dstch << 3)) = pack8(B0[q], B1[q]);
    }
    __syncthreads();
    if (kt < 31) issue(kt + 1);

#pragma unroll
    for (int s = 0; s < 2; ++s) {
      const int cs = s ? c1 : c0;
      bf16x8 a[4], b[4];
#pragma unroll
      for (int i = 0; i < 4; ++i) a[i] = *(const bf16x8*)(As + arow + i * 1024 + cs);
#pragma unroll
      for (int j = 0; j < 4; ++j) b[j] = *(const bf16x8*)(Bs + brow + j * 1024 + cs);
#pragma unroll
      for (int i = 0; i < 4; ++i)
#pragma unroll
        for (int j = 0; j < 4; ++j)
          acc[i][j] = __builtin_amdgcn_mfma_f32_16x16x32_bf16(a[i], b[j], acc[i][j], 0, 0, 0);
    }
  }

  const float* bAi = cq ? bgi : bfi;
  const float* bAh = cq ? bgh : bfh;
  const float* bBi = cq ? boi : bii;
  const float* bBh = cq ? boh : bih;
  float biasv[4];
  biasv[0] = bAi[hb + l15]      + bAh[hb + l15];
  biasv[1] = bAi[hb + 16 + l15] + bAh[hb + 16 + l15];
  biasv[2] = bBi[hb + l15]      + bBh[hb + l15];
  biasv[3] = bBi[hb + 16 + l15] + bBh[hb + 16 + l15];

  const size_t outCT = (size_t)8192 * 1024;

#pragma unroll
  for (int p = 0; p < 2; ++p) {
    __syncthreads();
    if (rq == p) {
#pragma unroll
      for (int j = 0; j < 4; ++j) {
        const int  n  = cq * 64 + j * 16 + l15;
        const bool ut = (cq == 1) && (j < 2);
        const float bj = biasv[j];
#pragma unroll
        for (int i = 0; i < 4; ++i)
#pragma unroll
          for (int r = 0; r < 4; ++r) {
            const float v = acc[i][j][r] + bj;
            Epi[(i * 16 + quad * 4 + r) * 132 + n] = ut ? ftanh(v) : fsigmoid(v);
          }
      }
    }
    __syncthreads();
#pragma unroll
    for (int it = 0; it < 8; ++it) {
      const int pair = it * 256 + tid;
      const int row  = pair >> 5;
      const int hl   = pair & 31;
      const float fv = Epi[row * 132 + hl];
      const float iv = Epi[row * 132 + 32 + hl];
      const float gv = Epi[row * 132 + 64 + hl];
      const float ov = Epi[row * 132 + 96 + hl];
      const size_t idx = (size_t)(bg0 + p * 64 + row) * 1024 + hb + hl;
      const float ctv = fv * c[idx] + iv * gv;
      const float htv = ov * ftanh(ctv);
      out[idx]         = htv;
      out[outCT + idx] = ctv;
    }
  }
}

extern "C" void kernel_launch(void* const* d_in, const int* in_sizes, int n_in,
                              void* d_out, int out_size, void* d_ws, size_t ws_size,
                              hipStream_t stream) {
  const float* p[19];
  for (int i = 0; i < 19; ++i) p[i] = (const float*)d_in[i];
  const size_t need = (size_t)24 * 1024 * 1024 * sizeof(bf16);   // 48 MB
  if (ws_size >= need) {
    prep_bf16<<<dim3(2048), dim3(256), 0, stream>>>(
        p[0], p[1],
        p[3], p[7], p[11], p[15],     // wfi wii wgi woi
        p[5], p[9], p[13], p[17],     // wfh wih wgh woh
        (bf16*)d_ws);
    lstm_mfma<<<dim3(512), dim3(512), 0, stream>>>(
        (const bf16*)d_ws, p[2],
        p[4], p[6], p[8], p[10], p[12], p[14], p[16], p[18],
        (float*)d_out);
  } else {
    lstm_fused<<<dim3(32, 64), dim3(256), 0, stream>>>(
        p[0], p[1], p[2],
        p[3], p[4], p[5], p[6],
        p[7], p[8], p[9], p[10],
        p[11], p[12], p[13], p[14],
        p[15], p[16], p[17], p[18],
        (float*)d_out);
  }
}